// Round 14
// baseline (963.226 us; speedup 1.0000x reference)
//
#include <hip/hip_runtime.h>
#include <hip/hip_bf16.h>
#include <math.h>

#define DEV __device__ __forceinline__

typedef __attribute__((ext_vector_type(8))) short short8;
typedef __attribute__((ext_vector_type(4))) float f32x4;
typedef __attribute__((ext_vector_type(4))) unsigned int u32x4;

static constexpr int Bsz  = 1024;
static constexpr int T    = 100;
static constexpr int TM1  = 99;
static constexpr int H    = 512;
static constexpr int OUTD = 64;
static constexpr int H2   = 1024;
static constexpr int BT   = Bsz * T;        // 102400

DEV unsigned short f2bf(float f){
  unsigned int u = __float_as_uint(f);
  u += 0x7fffu + ((u >> 16) & 1u);          // round-to-nearest-even
  return (unsigned short)(u >> 16);
}
DEV unsigned pack2(float lo, float hi){
  return (unsigned)f2bf(lo) | ((unsigned)f2bf(hi) << 16);
}
DEV float tanh_fast(float x){
  x = fminf(fmaxf(x, -15.f), 15.f);
  float e = __expf(2.f * x);
  return (e - 1.f) / (e + 1.f);
}

// data-path asm (see R6/R9 notes): sc0 sc1 = L3-coherent; sc0 = L2-cacheable
#define AISSUE_CC(dst, p) asm volatile("global_load_dwordx4 %0, %1, off sc0 sc1" : "=&v"(dst) : "v"(p) : "memory")
#define AISSUE_L2(dst, p) asm volatile("global_load_dwordx4 %0, %1, off sc0"     : "=&v"(dst) : "v"(p) : "memory")
#define PLOAD(dst, p)  asm volatile("global_load_dword %0, %1, off"          : "=&v"(dst) : "v"(p) : "memory")
#define SC_STORE(p, v) asm volatile("global_store_dword %0, %1, off sc0 sc1" :: "v"(p), "v"(v) : "memory")
#define VWAIT(n)       asm volatile("s_waitcnt vmcnt(" #n ")" ::: "memory"); __builtin_amdgcn_sched_barrier(0)

// fence-free 16-block group barrier; callers drain sc-stores (counted vmcnt) first
DEV void gbar(unsigned* cnt, unsigned target){
  __syncthreads();
  if (threadIdx.x == 0){
    __hip_atomic_fetch_add(cnt, 1u, __ATOMIC_RELAXED, __HIP_MEMORY_SCOPE_AGENT);
    while (__hip_atomic_load(cnt, __ATOMIC_RELAXED, __HIP_MEMORY_SCOPE_AGENT) < target)
      __builtin_amdgcn_s_sleep(1);
  }
  __syncthreads();
}

// ---------------- weight prep (identical to R13) ----------------
__global__ __launch_bounds__(256) void k_prep(const float* __restrict__ Wf1, const float* __restrict__ Wg1,
                                              const float* __restrict__ Wf2, const float* __restrict__ Wg2,
                                              const float* __restrict__ Wl1, const float* __restrict__ Wl2,
                                              unsigned short* __restrict__ W1T, unsigned short* __restrict__ W2T,
                                              unsigned short* __restrict__ Wl1F, unsigned short* __restrict__ Wl2F){
  __shared__ float tl[32][33];
  const float* src; unsigned short* dst; int N; int fmt;
  switch (blockIdx.z){
    case 0: src = Wf1; dst = W1T;             N = 512; fmt = 0; break;
    case 1: src = Wg1; dst = W1T + 512*512;   N = 512; fmt = 0; break;
    case 2: src = Wf2; dst = W2T;             N = 512; fmt = 0; break;
    case 3: src = Wg2; dst = W2T + 512*512;   N = 512; fmt = 0; break;
    case 4: src = Wl1; dst = Wl1F;            N = 512; fmt = 1; break;
    default: src = Wl2; dst = Wl2F;           N = 64;  fmt = 2; break;
  }
  int k0 = blockIdx.x*32, n0 = blockIdx.y*32;
  if (n0 >= N) return;
  int tx = threadIdx.x, ty = threadIdx.y;     // block (32,8)
  #pragma unroll
  for (int r = 0; r < 4; r++) tl[ty + r*8][tx] = src[(size_t)(k0 + ty + r*8) * N + n0 + tx];
  __syncthreads();
  if (fmt == 0){
    int kpos = k0 + ((tx & 15)*2 + (tx >> 4));   // sigma perm within 32-block
    #pragma unroll
    for (int r = 0; r < 4; r++) dst[(size_t)(n0 + ty + r*8) * 512 + kpos] = f2bf(tl[tx][ty + r*8]);
  } else {
    int k = k0 + tx;
    int Nc = (fmt == 1) ? 512 : 64;
    #pragma unroll
    for (int r = 0; r < 4; r++){
      int col = n0 + ty + r*8;
      size_t idx = (((size_t)(k >> 5)*Nc + col)*4 + ((k >> 3) & 3))*8 + (k & 7);
      dst[idx] = f2bf(tl[tx][ty + r*8]);
    }
  }
}

__global__ void k_zero(unsigned* __restrict__ cnts){
  cnts[threadIdx.x + blockIdx.x*256] = 0u;
}

// ---- 8-chunk half-K pipeline: issue all 8, consume with counted drain ----
#define KR8(K, W, LD) \
  VWAIT(W); \
  { short8 a_  = *(short8*)&ap[K]; \
    short8 b0_ = *(const short8*)(wbp + (size_t)(K)*4096); \
    short8 b1_ = *(const short8*)(wbp + (size_t)(K)*4096 + 1024); \
    p0 = __builtin_amdgcn_mfma_f32_16x16x32_bf16(a_, b0_, p0, 0,0,0); \
    p1 = __builtin_amdgcn_mfma_f32_16x16x32_bf16(a_, b1_, p1, 0,0,0); }

#define RUN8(LD) \
  LD(ap[0], abp);          LD(ap[1], abp+65536); \
  LD(ap[2], abp+131072);   LD(ap[3], abp+196608); \
  LD(ap[4], abp+262144);   LD(ap[5], abp+327680); \
  LD(ap[6], abp+393216);   LD(ap[7], abp+458752); \
  KR8(0,7,LD) KR8(1,6,LD) KR8(2,5,LD) KR8(3,4,LD) \
  KR8(4,3,LD) KR8(5,2,LD) KR8(6,1,LD) KR8(7,0,LD)

// ---------------- persistent group-synced scan v10: 16 waves, K-split ----------------
// 256 blocks x 1024 thr (16 waves = 4/SIMD). Same sync protocol as R9/R13
// (2 group barriers/step, 16-block groups). Intra-block: wave w -> band=w&3,
// isg=(w>>2)&1, kh=w>>3. kh=0: kc 0..7 (finisher), kh=1: kc 8..15 (writes f32
// partials to cmb). Phase1 finishers add+tanh+store u; phase2 f-adders reduce
// f in cmb, updaters reduce g and do the y update. Traffic identical to R13.
template<int UNIQ>
__global__ __launch_bounds__(1024, 1) void k_scan(
    const float* __restrict__ coeffs, const float* __restrict__ times,
    const float* __restrict__ dW,     const float* __restrict__ W_init,
    const float* __restrict__ b_init,
    const unsigned short* __restrict__ W1T, const unsigned short* __restrict__ W2T,
    const float* __restrict__ bf1, const float* __restrict__ bg1,
    const float* __restrict__ bf2, const float* __restrict__ bg2,
    unsigned short* __restrict__ ygk, unsigned short* __restrict__ uk,
    float* __restrict__ z, unsigned* __restrict__ cnts){
  __shared__ __align__(16) unsigned char W1s[65536];   // [16 kc][64 col][4 fq] x16B, XOR-swizzled
  __shared__ __align__(16) unsigned char W2s[65536];   // col<32 f-slice, col>=32 g-slice
  __shared__ __align__(16) float cmb[64*68];           // x0 stage / K-partials / f exchange
  __shared__ float tms[104];

  constexpr size_t YB = UNIQ ? (size_t)Bsz * H  * 2 : 0;   // 1 MB per step
  constexpr size_t UB = UNIQ ? (size_t)Bsz * H2 * 2 : 0;   // 2 MB per step

  const int bid = blockIdx.x, mt = bid & 15, ns = bid >> 4;
  const int m0 = mt*64, n1 = ns*64, n2 = ns*32;
  const int tid = threadIdx.x, lane = tid & 63, w = tid >> 6;
  const int fr = lane & 15, fq = lane >> 4;
  const int band = w & 3, isg = (w >> 2) & 1, kh = w >> 3;
  unsigned* cnt = cnts + mt*32;
  unsigned ep = 0;

  // ---- stage weight slices into LDS (frag-major, XOR bank swizzle) ----
  #pragma unroll
  for (int i = 0; i < 4; i++){
    int u = i*1024 + tid;                    // unit = (kc*64+cl)*4+fqi
    int fqi = u & 3, cl = (u >> 2) & 63, kc = u >> 8;
    size_t dstoff = (size_t)kc*4096 + (size_t)((cl*64 + fqi*16) ^ ((cl & 7) << 4));
    *(uint4*)(W1s + dstoff) = *(const uint4*)(W1T + (size_t)(n1+cl)*512 + kc*32 + fqi*8);
    const unsigned short* s2 = (cl < 32) ? (W2T + (size_t)(n2+cl)*512)
                                         : (W2T + (size_t)262144 + (size_t)(n2+cl-32)*512);
    *(uint4*)(W2s + dstoff) = *(const uint4*)(s2 + kc*32 + fqi*8);
  }
  if (tid < 100) tms[tid] = times[tid];
  { int row = tid >> 4, c0 = (tid & 15)*4;
    const float* src = coeffs + (size_t)(m0+row)*(TM1*4*64) + c0;
    *(float4*)(&cmb[row*68 + c0]) = *(const float4*)src;
  }
  __syncthreads();

  // per-lane pointers; this wave consumes chunks kh*8 .. kh*8+7
  char* ygkb = (char*)ygk;
  char* ukb  = (char*)uk;
  const char* ab1k = ygkb + ((size_t)(m0 + band*16 + fr))*64 + fq*16 + (size_t)kh*8*65536;
  const char* ab2k = ukb + (size_t)isg*1048576 + ((size_t)(m0 + band*16 + fr))*64 + fq*16
                     + (size_t)kh*8*65536;
  char* up = ukb  + (size_t)(ns*2 + isg)*65536 + ((size_t)(m0 + band*16 + fq*4))*64 + fr*4;
  char* yp = ygkb + (size_t)ns*65536           + ((size_t)(m0 + band*16 + fq*4))*64 + fr*4;
  const unsigned char* wbp1 = W1s + (size_t)kh*32768 + isg*2048
                              + (size_t)((fr*64 + fq*16) ^ ((fr & 7) << 4));
  const unsigned char* wbp2 = W2s + (size_t)kh*32768 + isg*2048
                              + (size_t)((fr*64 + fq*16) ^ ((fr & 7) << 4));
  float* zp = z + ((size_t)(m0 + band*16 + fq*4))*T*512 + n2 + fr;

  // biases (finishers/adders only use these)
  const float* b1src = (ns < 8) ? bf1 : bg1;
  const int    b1off = n1 - ((ns < 8) ? 0 : 512) + isg*32 + fr;
  const float b1v0 = b1src[b1off], b1v1 = b1src[b1off + 16];
  const float* b2src = isg ? bg2 : bf2;
  const float b2v0 = b2src[n2 + fr], b2v1 = b2src[n2 + 16 + fr];

  // ---- init: y0 = x0 @ W_init + b_init (updater waves 4..7) -> y buffer 0 ----
  float yv[2][4];
  if (kh == 0 && isg == 1){
    #pragma unroll
    for (int r = 0; r < 4; r++){
      int lrow = band*16 + fq*4 + r;
      float s0 = b_init[n2 + fr], s1 = b_init[n2 + 16 + fr];
      #pragma unroll 8
      for (int k = 0; k < 64; k++){
        float xv = cmb[lrow*68 + k];
        s0 += xv * W_init[(size_t)k*512 + n2 + fr];
        s1 += xv * W_init[(size_t)k*512 + n2 + 16 + fr];
      }
      yv[0][r] = s0; yv[1][r] = s1;
      SC_STORE(yp + r*64, pack2(s0, s1));
      zp[(size_t)r*T*512]      = s0;
      zp[(size_t)r*T*512 + 16] = s1;
    }
    VWAIT(8);                                // 4 y-sc complete; z may linger
  }
  ++ep; gbar(cnt, ep*16);

  for (int t = 0; t < TM1; t++){
    float dv[8];
    // ===== phase 1: u(t) = tanh(y(t) @ W1 + b1), K split across kh =====
    {
      f32x4 p0 = {0.f,0.f,0.f,0.f}, p1 = {0.f,0.f,0.f,0.f};
      u32x4 ap[8];
      const char* abp = ab1k + (size_t)t*YB;
      const unsigned char* wbp = wbp1;
      if constexpr (UNIQ) { RUN8(AISSUE_L2); } else { RUN8(AISSUE_CC); }
      if (kh){                               // writer: stash K-half partials
        #pragma unroll
        for (int r = 0; r < 4; r++){
          int lrow = band*16 + fq*4 + r;
          cmb[lrow*68 + isg*32 + fr]      = p0[r];
          cmb[lrow*68 + isg*32 + 16 + fr] = p1[r];
        }
      }
      __syncthreads();
      if (!kh){                              // finisher: reduce + bias + tanh + store
        char* upt = up + (size_t)t*UB;
        #pragma unroll
        for (int r = 0; r < 4; r++){
          int lrow = band*16 + fq*4 + r;
          float s0 = p0[r] + cmb[lrow*68 + isg*32 + fr]      + b1v0;
          float s1 = p1[r] + cmb[lrow*68 + isg*32 + 16 + fr] + b1v1;
          SC_STORE(upt + r*64, pack2(tanh_fast(s0), tanh_fast(s1)));
        }
        if (isg){                            // updater waves: dW prefetch under barrier
          const char* dp = (const char*)dW + (((size_t)t*1024 + m0 + band*16 + fq*4)*512 + n2 + fr)*4;
          PLOAD(dv[0], dp + 0);      PLOAD(dv[1], dp + 64);
          PLOAD(dv[2], dp + 2048);   PLOAD(dv[3], dp + 2048+64);
          PLOAD(dv[4], dp + 4096);   PLOAD(dv[5], dp + 4096+64);
          PLOAD(dv[6], dp + 6144);   PLOAD(dv[7], dp + 6144+64);
          VWAIT(8);                          // 4 u-sc complete; dW in flight
        } else {
          VWAIT(0);
        }
      }
    }
    ++ep; gbar(cnt, ep*16);

    // ===== phase 2: f = u_f@Wf2, g = u_g@Wg2 (K split), reduce, y update =====
    {
      f32x4 p0 = {0.f,0.f,0.f,0.f}, p1 = {0.f,0.f,0.f,0.f};
      u32x4 ap[8];
      const char* abp = ab2k + (size_t)t*UB;
      const unsigned char* wbp = wbp2;
      if constexpr (UNIQ) { RUN8(AISSUE_L2); } else { RUN8(AISSUE_CC); }
      if (kh){                               // writers: f partials @cols 0..31, g @32..63
        #pragma unroll
        for (int r = 0; r < 4; r++){
          int lrow = band*16 + fq*4 + r;
          cmb[lrow*68 + isg*32 + fr]      = p0[r];
          cmb[lrow*68 + isg*32 + 16 + fr] = p1[r];
        }
      }
      __syncthreads();
      if (!kh && !isg){                      // f-adder: full f (in place, own-address RMW)
        #pragma unroll
        for (int r = 0; r < 4; r++){
          int lrow = band*16 + fq*4 + r;
          cmb[lrow*68 + fr]      = p0[r] + cmb[lrow*68 + fr]      + b2v0;
          cmb[lrow*68 + 16 + fr] = p1[r] + cmb[lrow*68 + 16 + fr] + b2v1;
        }
      }
      __syncthreads();
      if (!kh && isg){                       // updater: full g + y update + stores
        float h  = tms[t+1] - tms[t];
        float sq = sqrtf(h);
        char* ypt = yp + (size_t)(t+1)*YB;
        #pragma unroll
        for (int r = 0; r < 4; r++){
          int lrow = band*16 + fq*4 + r;
          float f0 = cmb[lrow*68 + fr],      f1 = cmb[lrow*68 + 16 + fr];
          float g0 = tanh_fast(p0[r] + cmb[lrow*68 + 32 + fr] + b2v0);
          float g1 = tanh_fast(p1[r] + cmb[lrow*68 + 48 + fr] + b2v1);
          float y0n = yv[0][r] + f0*h + g0*(sq*dv[r*2]);
          float y1n = yv[1][r] + f1*h + g1*(sq*dv[r*2+1]);
          yv[0][r] = y0n; yv[1][r] = y1n;
          SC_STORE(ypt + r*64, pack2(y0n, y1n));
          zp[(size_t)r*T*512 + (size_t)(t+1)*512]      = y0n;
          zp[(size_t)r*T*512 + (size_t)(t+1)*512 + 16] = y1n;
        }
        VWAIT(8);                            // 4 y-sc complete; z may linger
      }
    }
    if (t < TM1-1){ ++ep; gbar(cnt, ep*16); }
  }
}

// ---------------- fused readout (identical to R13) ----------------
__global__ __launch_bounds__(512, 1) void k_read(
    const float* __restrict__ z, const unsigned short* __restrict__ Wl1F,
    const float* __restrict__ bl1, const unsigned short* __restrict__ Wl2F,
    const float* __restrict__ bl2, float* __restrict__ out){
  __shared__ __align__(16) unsigned char zt[65536];
  __shared__ __align__(16) unsigned char relF[65536];
  const int tid = threadIdx.x, lane = tid & 63, w = tid >> 6;
  const int fr = lane & 15, fq = lane >> 4;
  const size_t rr0 = (size_t)blockIdx.x * 64;
  const int cw = w * 64;

  { int row = tid >> 3, c0 = (tid & 7) * 64;
    const float* zr = z + (rr0 + row) * 512 + c0;
    #pragma unroll
    for (int j = 0; j < 2; ++j){
      int kc = (c0 >> 5) + j;
      #pragma unroll
      for (int f = 0; f < 4; ++f){
        float4 v0 = *(const float4*)(zr + j*32 + f*8);
        float4 v1 = *(const float4*)(zr + j*32 + f*8 + 4);
        unsigned d0 = pack2(tanh_fast(v0.x), tanh_fast(v0.y));
        unsigned d1 = pack2(tanh_fast(v0.z), tanh_fast(v0.w));
        unsigned d2 = pack2(tanh_fast(v1.x), tanh_fast(v1.y));
        unsigned d3 = pack2(tanh_fast(v1.z), tanh_fast(v1.w));
        uint4 pk = {d0, d1, d2, d3};
        *(uint4*)(zt + (size_t)((kc*64 + row)*4 + f)*16) = pk;
      }
    }
  }
  __syncthreads();

  f32x4 acc[4][4];
  #pragma unroll
  for (int m = 0; m < 4; m++)
    #pragma unroll
    for (int c = 0; c < 4; c++) acc[m][c] = (f32x4){0.f,0.f,0.f,0.f};
  for (int kc = 0; kc < 16; ++kc){
    short8 a[4];
    #pragma unroll
    for (int m = 0; m < 4; m++)
      a[m] = *(const short8*)(zt + (size_t)((kc*64 + m*16 + fr)*4 + fq)*16);
    #pragma unroll
    for (int c = 0; c < 4; c++){
      short8 b = *(const short8*)(Wl1F + (((size_t)kc*512 + cw + c*16 + fr)*4 + fq)*8);
      #pragma unroll
      for (int m = 0; m < 4; m++)
        acc[m][c] = __builtin_amdgcn_mfma_f32_16x16x32_bf16(a[m], b, acc[m][c], 0, 0, 0);
    }
  }
  float bl1v[4];
  #pragma unroll
  for (int c = 0; c < 4; c++) bl1v[c] = bl1[cw + c*16 + fr];

  #pragma unroll
  for (int h = 0; h < 2; ++h){
    __syncthreads();
    if ((w >> 2) == h){
      float* stg = (float*)zt;
      int cb = cw - h*256;
      #pragma unroll
      for (int m = 0; m < 4; m++)
        #pragma unroll
        for (int c = 0; c < 4; c++)
          #pragma unroll
          for (int r = 0; r < 4; r++)
            stg[(m*16 + fq*4 + r)*256 + cb + c*16 + fr] = fmaxf(acc[m][c][r] + bl1v[c], 0.f);
    }
    __syncthreads();
    { int row = tid >> 3, c8 = (tid & 7) * 32;
      const float* stg = (const float*)zt;
      int kc = h*8 + (tid & 7);
      #pragma unroll
      for (int f = 0; f < 4; ++f){
        const float* p = stg + row*256 + c8 + f*8;
        unsigned d0 = pack2(p[0], p[1]);
        unsigned d1 = pack2(p[2], p[3]);
        unsigned d2 = pack2(p[4], p[5]);
        unsigned d3 = pack2(p[6], p[7]);
        uint4 pk = {d0, d1, d2, d3};
        *(uint4*)(relF + (size_t)((kc*64 + row)*4 + f)*16) = pk;
      }
    }
  }
  __syncthreads();

  f32x4 acc2[2];
  acc2[0] = (f32x4){0.f,0.f,0.f,0.f};
  acc2[1] = (f32x4){0.f,0.f,0.f,0.f};
  const int mt2 = w & 3, ocb = (w >> 2) * 32;
  for (int kc = 0; kc < 16; ++kc){
    short8 a = *(const short8*)(relF + (size_t)((kc*64 + mt2*16 + fr)*4 + fq)*16);
    #pragma unroll
    for (int j = 0; j < 2; j++){
      short8 b = *(const short8*)(Wl2F + (((size_t)(kc*64 + ocb + j*16 + fr))*4 + fq)*8);
      acc2[j] = __builtin_amdgcn_mfma_f32_16x16x32_bf16(a, b, acc2[j], 0, 0, 0);
    }
  }
  #pragma unroll
  for (int j = 0; j < 2; j++){
    #pragma unroll
    for (int r = 0; r < 4; r++){
      int row = mt2*16 + fq*4 + r;
      int oc  = ocb + j*16 + fr;
      out[(rr0 + row)*64 + oc] = acc2[j][r] + bl2[oc];
    }
  }
}

extern "C" void kernel_launch(void* const* d_in, const int* in_sizes, int n_in,
                              void* d_out, int out_size, void* d_ws, size_t ws_size,
                              hipStream_t stream){
  (void)in_sizes; (void)n_in; (void)out_size;
  const float* coeffs = (const float*)d_in[0];
  const float* times  = (const float*)d_in[1];
  const float* dW     = (const float*)d_in[2];
  const float* W_init = (const float*)d_in[3];
  const float* b_init = (const float*)d_in[4];
  const float* Wf1 = (const float*)d_in[5];
  const float* bf1 = (const float*)d_in[6];
  const float* Wf2 = (const float*)d_in[7];
  const float* bf2 = (const float*)d_in[8];
  const float* Wg1 = (const float*)d_in[9];
  const float* bg1 = (const float*)d_in[10];
  const float* Wg2 = (const float*)d_in[11];
  const float* bg2 = (const float*)d_in[12];
  const float* Wl1 = (const float*)d_in[13];
  const float* bl1 = (const float*)d_in[14];
  const float* Wl2 = (const float*)d_in[15];
  const float* bl2 = (const float*)d_in[16];

  float* out = (float*)d_out;
  float* z   = out + (size_t)Bsz * T * OUTD;   // z region of d_out, (B,T,H)

  // step-unique layout needs ~302 MB of workspace
  const bool full = ws_size >= ((size_t)320 << 20);

  char* wsp = (char*)d_ws;
  auto carve = [&](size_t bytes) -> void* {
    void* p = (void*)wsp; wsp += (bytes + 255) & ~(size_t)255; return p;
  };
  unsigned short* W1T  = (unsigned short*)carve((size_t)H2 * H * 2);
  unsigned short* W2T  = (unsigned short*)carve((size_t)H2 * H * 2);
  unsigned short* Wl1F = (unsigned short*)carve((size_t)H * H * 2);
  unsigned short* Wl2F = (unsigned short*)carve((size_t)OUTD * H * 2);
  unsigned short* ygk  = (unsigned short*)carve(full ? (size_t)T   * Bsz * H  * 2
                                                     : (size_t)Bsz * H  * 2);
  unsigned short* uk   = (unsigned short*)carve(full ? (size_t)TM1 * Bsz * H2 * 2
                                                     : (size_t)Bsz * H2 * 2);
  unsigned*       cnts = (unsigned*)carve(1024 * sizeof(unsigned));

  k_zero<<<dim3(4), 256, 0, stream>>>(cnts);
  k_prep<<<dim3(16, 16, 6), dim3(32, 8), 0, stream>>>(Wf1, Wg1, Wf2, Wg2, Wl1, Wl2,
                                                      W1T, W2T, Wl1F, Wl2F);
  if (full)
    k_scan<1><<<dim3(256), 1024, 0, stream>>>(coeffs, times, dW, W_init, b_init,
                                              W1T, W2T, bf1, bg1, bf2, bg2,
                                              ygk, uk, z, cnts);
  else
    k_scan<0><<<dim3(256), 1024, 0, stream>>>(coeffs, times, dW, W_init, b_init,
                                              W1T, W2T, bf1, bg1, bf2, bg2,
                                              ygk, uk, z, cnts);
  k_read<<<dim3(BT / 64), 512, 0, stream>>>(z, Wl1F, bl1, Wl2F, bl2, out);
}